// Round 1
// baseline (285.606 us; speedup 1.0000x reference)
//
#include <hip/hip_runtime.h>
#include <math.h>

#define NQ    8192
#define NPTS  32768
#define CDIM  128
#define KNN   64
#define QPB   16            // queries per block
#define TILE  2048          // points staged in LDS per tile
#define NTILE (NPTS / TILE) // 16
#define CAP   224           // candidate list capacity per query
#define NBLK  (NQ / QPB)    // 512 blocks -> exactly 2 per CU resident

// ---- order-preserving float<->uint key (total order incl. negatives) ----
__device__ __forceinline__ unsigned key_of(float f) {
  unsigned u = __float_as_uint(f);
  return (u & 0x80000000u) ? ~u : (u | 0x80000000u);
}
__device__ __forceinline__ float val_of(unsigned k) {
  unsigned u = (k & 0x80000000u) ? (k & 0x7fffffffu) : ~k;
  return __uint_as_float(u);
}

__device__ __forceinline__ float norm_cdf(float x) { return 0.5f * erfcf(-x * 0.70710678f); }

// Mass of standard 3D gaussian inside ball of radius r centered at distance mu.
// Exact closed form; count(d < r) ~ Binomial(N, mass) for iid points.
__device__ __forceinline__ float ball_mass(float mu, float r) {
  float a = r - mu, b = r + mu;
  float e = __expf(-0.5f * b * b) - __expf(-0.5f * a * a);
  return e / (mu * 2.50662827f) + norm_cdf(a) - norm_cdf(-mu) + norm_cdf(b) - norm_cdf(mu);
}

__device__ __forceinline__ int wave_sum(int v) {
  #pragma unroll
  for (int m = 32; m; m >>= 1) v += __shfl_xor(v, m, 64);
  return v;
}

__global__ __launch_bounds__(256, 2) void ft_knn_kernel(
    const float* __restrict__ qpos, const float* __restrict__ feat,
    const float* __restrict__ pos, float* __restrict__ out) {

  __shared__ float    sX[TILE], sY[TILE], sZ[TILE];
  __shared__ unsigned sCandK[QPB][CAP];
  __shared__ int      sCandI[QPB][CAP];
  __shared__ int      sFidx[QPB][KNN];
  __shared__ float    sFw[QPB][KNN];
  __shared__ float    sQx[QPB], sQy[QPB], sQz[QPB], sQ2[QPB];
  __shared__ float    sTau[QPB], sTlo[QPB], sThi[QPB];
  __shared__ int      sCnt[QPB], sAct[QPB], sSel[QPB], sAny;

  const int tid   = threadIdx.x;
  const int lane  = tid & 63;
  const int wv    = tid >> 6;            // 4 waves
  const int qbase = blockIdx.x * QPB;
  const int lq0   = wv * 4;              // this wave owns block-local queries lq0..lq0+3

  // ---- per-query init: load query, solve tau from gaussian model ----
  if (tid < QPB) {
    int gq = qbase + tid;
    float x = qpos[gq * 3 + 0], y = qpos[gq * 3 + 1], z = qpos[gq * 3 + 2];
    sQx[tid] = x; sQy[tid] = y; sQz[tid] = z;
    float q2 = x * x + y * y + z * z;
    sQ2[tid] = q2;
    float mu = fmaxf(sqrtf(q2), 0.05f);
    const float target = 140.0f / 32768.0f;   // expected candidate count 140 (64 < 140-6sig, 224 > 140+6sig)
    float lo = 0.f, hi = mu + 8.f;
    for (int i = 0; i < 30; ++i) {
      float r = 0.5f * (lo + hi);
      if (ball_mass(mu, r) < target) lo = r; else hi = r;
    }
    sTau[tid] = hi * hi;
    sTlo[tid] = 0.f; sThi[tid] = -1.f;   // -1 == no upper bound yet
    sCnt[tid] = 0;   sAct[tid] = 1;
  }
  __syncthreads();

  // ---- candidate collection pass (re-run with refined tau if model missed; ~always 1 pass) ----
  for (int attempt = 0; attempt < 12; ++attempt) {
    float qxn[4], qyn[4], qzn[4], q2v[4], tauv[4]; int actv[4];
    #pragma unroll
    for (int q = 0; q < 4; ++q) {
      qxn[q] = -2.f * sQx[lq0 + q]; qyn[q] = -2.f * sQy[lq0 + q]; qzn[q] = -2.f * sQz[lq0 + q];
      q2v[q] = sQ2[lq0 + q]; tauv[q] = sTau[lq0 + q]; actv[q] = sAct[lq0 + q];
    }
    const int anyAct = actv[0] | actv[1] | actv[2] | actv[3];

    for (int t = 0; t < NTILE; ++t) {
      __syncthreads();  // previous tile consumers done
      {   // stage tile: 8 points per thread, coalesced-ish 12B-stride reads
        const float* src = pos + (size_t)t * TILE * 3;
        #pragma unroll
        for (int i = 0; i < TILE / 256; ++i) {
          int p = i * 256 + tid;
          float px = src[p * 3 + 0], py = src[p * 3 + 1], pz = src[p * 3 + 2];
          sX[p] = px; sY[p] = py; sZ[p] = pz;
        }
      }
      __syncthreads();
      if (!anyAct) continue;

      for (int g = 0; g < TILE / 256; ++g) {
        const int pi = g * 256 + lane * 4;
        const float4 X = *(const float4*)&sX[pi];
        const float4 Y = *(const float4*)&sY[pi];
        const float4 Z = *(const float4*)&sZ[pi];
        const float p2a = X.x * X.x + Y.x * Y.x + Z.x * Z.x;
        const float p2b = X.y * X.y + Y.y * Y.y + Z.y * Z.y;
        const float p2c = X.z * X.z + Y.z * Y.z + Z.z * Z.z;
        const float p2d = X.w * X.w + Y.w * Y.w + Z.w * Z.w;
        #pragma unroll
        for (int q = 0; q < 4; ++q) {
          if (!actv[q]) continue;
          const float b = q2v[q];
          float d0 = fmaf(Z.x, qzn[q], fmaf(Y.x, qyn[q], fmaf(X.x, qxn[q], b + p2a)));
          float d1 = fmaf(Z.y, qzn[q], fmaf(Y.y, qyn[q], fmaf(X.y, qxn[q], b + p2b)));
          float d2 = fmaf(Z.z, qzn[q], fmaf(Y.z, qyn[q], fmaf(X.z, qxn[q], b + p2c)));
          float d3 = fmaf(Z.w, qzn[q], fmaf(Y.w, qyn[q], fmaf(X.w, qxn[q], b + p2d)));
          bool h0 = d0 < tauv[q], h1 = d1 < tauv[q], h2 = d2 < tauv[q], h3 = d3 < tauv[q];
          if (h0 | h1 | h2 | h3) {
            const int pt = t * TILE + pi;
            const int lq = lq0 + q;
            int* cq = &sCnt[lq];
            if (h0) { int p = atomicAdd(cq, 1); if (p < CAP) { sCandK[lq][p] = key_of(d0); sCandI[lq][p] = pt + 0; } }
            if (h1) { int p = atomicAdd(cq, 1); if (p < CAP) { sCandK[lq][p] = key_of(d1); sCandI[lq][p] = pt + 1; } }
            if (h2) { int p = atomicAdd(cq, 1); if (p < CAP) { sCandK[lq][p] = key_of(d2); sCandI[lq][p] = pt + 2; } }
            if (h3) { int p = atomicAdd(cq, 1); if (p < CAP) { sCandK[lq][p] = key_of(d3); sCandI[lq][p] = pt + 3; } }
          }
        }
      }
    }
    __syncthreads();
    if (tid == 0) sAny = 0;
    __syncthreads();
    if (tid < QPB && sAct[tid]) {
      int c = sCnt[tid];
      if (c >= KNN && c <= CAP) { sAct[tid] = 0; }
      else {
        if (c < KNN) { sTlo[tid] = sTau[tid];
                       sTau[tid] = (sThi[tid] < 0.f) ? sTau[tid] * 3.f : 0.5f * (sTau[tid] + sThi[tid]); }
        else         { sThi[tid] = sTau[tid];
                       sTau[tid] = 0.5f * (sTlo[tid] + sTau[tid]); }
        sCnt[tid] = 0;
        sAny = 1;
      }
    }
    __syncthreads();
    if (!sAny) break;
  }

  if (tid < QPB) sSel[tid] = 0;
  __syncthreads();

  // ---- exact select (bisection on uint key), weights, feature accumulation ----
  for (int q = 0; q < 4; ++q) {
    const int lq = lq0 + q;
    const int gq = qbase + lq;
    const int m  = min(sCnt[lq], CAP);

    if (m > KNN) {
      unsigned lo = 0u, hi = 0xffffffffu;
      for (int it = 0; it < 32; ++it) {
        unsigned mid = lo + ((hi - lo) >> 1);
        int c = 0;
        for (int j = lane; j < m; j += 64) c += (sCandK[lq][j] <= mid) ? 1 : 0;
        c = wave_sum(c);
        if (c >= KNN) hi = mid; else lo = mid + 1;
      }
      const unsigned K = lo;  // exact 64th-smallest key
      for (int j = lane; j < m; j += 64) {
        unsigned k = sCandK[lq][j];
        if (k < K) {
          int p = atomicAdd(&sSel[lq], 1);
          float dv = val_of(k);
          sFidx[lq][p] = sCandI[lq][j];
          sFw[lq][p]   = 1.f / (sqrtf(fmaxf(dv, 1e-12f)) + 1e-5f);
        }
      }
      for (int j = lane; j < m; j += 64) {   // fill remaining slots from ties at K
        unsigned k = sCandK[lq][j];
        if (k == K) {
          int p = atomicAdd(&sSel[lq], 1);
          if (p < KNN) {
            float dv = val_of(k);
            sFidx[lq][p] = sCandI[lq][j];
            sFw[lq][p]   = 1.f / (sqrtf(fmaxf(dv, 1e-12f)) + 1e-5f);
          }
        }
      }
    } else {  // degenerate safety path: take everything we have
      for (int j = lane; j < m; j += 64) {
        unsigned k = sCandK[lq][j];
        int p = atomicAdd(&sSel[lq], 1);
        float dv = val_of(k);
        sFidx[lq][p] = sCandI[lq][j];
        sFw[lq][p]   = 1.f / (sqrtf(fmaxf(dv, 1e-12f)) + 1e-5f);
      }
    }
    // pad unused slots (never happens in the healthy path)
    int sc = min(sSel[lq], KNN);
    if (lane >= sc) { sFw[lq][lane] = 0.f; sFidx[lq][lane] = 0; }

    // weighted feature sum: each lane owns 2 channels
    float ax = 0.f, ay = 0.f;
    #pragma unroll 4
    for (int j = 0; j < KNN; ++j) {
      int   id = sFidx[lq][j];
      float w  = sFw[lq][j];
      const float2 f2 = *(const float2*)(feat + ((size_t)id << 7) + (lane << 1));
      ax = fmaf(w, f2.x, ax);
      ay = fmaf(w, f2.y, ay);
    }
    *(float2*)(out + ((size_t)gq << 7) + (lane << 1)) = make_float2(ax, ay);
  }
}

extern "C" void kernel_launch(void* const* d_in, const int* in_sizes, int n_in,
                              void* d_out, int out_size, void* d_ws, size_t ws_size,
                              hipStream_t stream) {
  const float* qpos = (const float*)d_in[0];   // [8192,3]
  const float* feat = (const float*)d_in[1];   // [32768,128]
  const float* pos  = (const float*)d_in[2];   // [32768,3]
  float* out = (float*)d_out;                  // [8192,128]
  ft_knn_kernel<<<dim3(NBLK), dim3(256), 0, stream>>>(qpos, feat, pos, out);
}

// Round 2
// 217.589 us; speedup vs baseline: 1.3126x; 1.3126x over previous
//
#include <hip/hip_runtime.h>
#include <math.h>

#define NQ    8192
#define NPTS  32768
#define CDIM  128
#define KNN   64
#define QPB   8             // queries per block
#define CAP   224           // candidate capacity per query (E[count]=140, +7 sigma)
#define NBLK  (NQ / QPB)    // 1024 blocks -> 4 resident/CU (LDS ~19KB, cap 8)
#define PPW   (NPTS / 4)    // each of 4 waves scans a quarter of the points
#define NGRP  (PPW / 256)   // 32 groups of (64 lanes x 4 points)

// ---- order-preserving float<->uint key ----
__device__ __forceinline__ unsigned key_of(float f) {
  unsigned u = __float_as_uint(f);
  return (u & 0x80000000u) ? ~u : (u | 0x80000000u);
}
__device__ __forceinline__ float val_of(unsigned k) {
  unsigned u = (k & 0x80000000u) ? (k & 0x7fffffffu) : ~k;
  return __uint_as_float(u);
}

__device__ __forceinline__ float norm_cdf(float x) { return 0.5f * erfcf(-x * 0.70710678f); }

// Mass of standard 3D gaussian inside ball radius r centered at distance mu.
__device__ __forceinline__ float ball_mass(float mu, float r) {
  float a = r - mu, b = r + mu;
  float e = __expf(-0.5f * b * b) - __expf(-0.5f * a * a);
  return e / (mu * 2.50662827f) + norm_cdf(a) - norm_cdf(-mu) + norm_cdf(b) - norm_cdf(mu);
}

__device__ __forceinline__ int wave_sum(int v) {
  #pragma unroll
  for (int m = 32; m; m >>= 1) v += __shfl_xor(v, m, 64);
  return v;
}

__global__ __launch_bounds__(256, 4) void ft_knn_kernel(
    const float* __restrict__ qpos, const float* __restrict__ feat,
    const float* __restrict__ pos, float* __restrict__ out) {

  __shared__ unsigned sCandK[QPB][CAP];
  __shared__ int      sCandI[QPB][CAP];
  __shared__ int      sFidx[QPB][KNN];
  __shared__ float    sFw[QPB][KNN];
  __shared__ float    sQx[QPB], sQy[QPB], sQz[QPB], sQ2[QPB];
  __shared__ float    sTau[QPB], sTlo[QPB], sThi[QPB];
  __shared__ int      sCnt[QPB], sAct[QPB], sSel[QPB], sAny;

  const int tid   = threadIdx.x;
  const int lane  = tid & 63;
  const int wv    = tid >> 6;      // 4 waves; wave wv scans points [wv*PPW, (wv+1)*PPW)
  const int qbase = blockIdx.x * QPB;

  // ---- per-query init: gaussian-model tau ----
  if (tid < QPB) {
    int gq = qbase + tid;
    float x = qpos[gq * 3 + 0], y = qpos[gq * 3 + 1], z = qpos[gq * 3 + 2];
    sQx[tid] = x; sQy[tid] = y; sQz[tid] = z;
    float q2 = x * x + y * y + z * z;
    sQ2[tid] = q2;
    float mu = fmaxf(sqrtf(q2), 0.05f);
    const float target = 140.0f / 32768.0f;
    float lo = 0.f, hi = mu + 8.f;
    for (int i = 0; i < 20; ++i) {
      float r = 0.5f * (lo + hi);
      if (ball_mass(mu, r) < target) lo = r; else hi = r;
    }
    sTau[tid] = hi * hi;
    sTlo[tid] = 0.f; sThi[tid] = -1.f;
    sCnt[tid] = 0;   sAct[tid] = 1;
  }
  __syncthreads();

  // ---- candidate scan (retry with refined tau if model missed; ~always 1 pass) ----
  for (int attempt = 0; attempt < 12; ++attempt) {
    float qxn[QPB], qyn[QPB], qzn[QPB], qb[QPB], tauv[QPB];
    int anyAct = 0;
    #pragma unroll
    for (int q = 0; q < QPB; ++q) {
      qxn[q] = -2.f * sQx[q]; qyn[q] = -2.f * sQy[q]; qzn[q] = -2.f * sQz[q];
      qb[q]  = sQ2[q];
      // finished queries get tau=-inf => no hits, no branch needed in hot loop
      tauv[q] = sAct[q] ? sTau[q] : -1e30f;
      anyAct |= sAct[q];
    }
    if (anyAct) {
      const int pw = wv * PPW;
      for (int g = 0; g < NGRP; ++g) {
        const int pt = pw + g * 256 + lane * 4;
        const float* bp = pos + (size_t)pt * 3;
        const float4 A  = *(const float4*)(bp);
        const float4 B  = *(const float4*)(bp + 4);
        const float4 Cc = *(const float4*)(bp + 8);
        const float x0 = A.x,  y0 = A.y,  z0 = A.z;
        const float x1 = A.w,  y1 = B.x,  z1 = B.y;
        const float x2 = B.z,  y2 = B.w,  z2 = Cc.x;
        const float x3 = Cc.y, y3 = Cc.z, z3 = Cc.w;
        const float n0 = x0 * x0 + y0 * y0 + z0 * z0;
        const float n1 = x1 * x1 + y1 * y1 + z1 * z1;
        const float n2 = x2 * x2 + y2 * y2 + z2 * z2;
        const float n3 = x3 * x3 + y3 * y3 + z3 * z3;
        #pragma unroll
        for (int q = 0; q < QPB; ++q) {
          const float b = qb[q];
          float d0 = fmaf(z0, qzn[q], fmaf(y0, qyn[q], fmaf(x0, qxn[q], b + n0)));
          float d1 = fmaf(z1, qzn[q], fmaf(y1, qyn[q], fmaf(x1, qxn[q], b + n1)));
          float d2 = fmaf(z2, qzn[q], fmaf(y2, qyn[q], fmaf(x2, qxn[q], b + n2)));
          float d3 = fmaf(z3, qzn[q], fmaf(y3, qyn[q], fmaf(x3, qxn[q], b + n3)));
          const bool h0 = d0 < tauv[q], h1 = d1 < tauv[q], h2 = d2 < tauv[q], h3 = d3 < tauv[q];
          const int hm = (h0 ? 1 : 0) | (h1 ? 2 : 0) | (h2 ? 4 : 0) | (h3 ? 8 : 0);
          if (hm) {  // rare (~1 lane per wave per q-group); single atomic, parallel stores
            int p0 = atomicAdd(&sCnt[q], __popc(hm));
            if (h0) { int p = p0;                 if (p < CAP) { sCandK[q][p] = key_of(d0); sCandI[q][p] = pt + 0; } }
            if (h1) { int p = p0 + (hm & 1);      if (p < CAP) { sCandK[q][p] = key_of(d1); sCandI[q][p] = pt + 1; } }
            if (h2) { int p = p0 + __popc(hm & 3); if (p < CAP) { sCandK[q][p] = key_of(d2); sCandI[q][p] = pt + 2; } }
            if (h3) { int p = p0 + __popc(hm & 7); if (p < CAP) { sCandK[q][p] = key_of(d3); sCandI[q][p] = pt + 3; } }
          }
        }
      }
    }
    __syncthreads();
    if (tid == 0) sAny = 0;
    __syncthreads();
    if (tid < QPB && sAct[tid]) {
      int c = sCnt[tid];
      if (c >= KNN && c <= CAP) { sAct[tid] = 0; }
      else {
        if (c < KNN) { sTlo[tid] = sTau[tid];
                       sTau[tid] = (sThi[tid] < 0.f) ? sTau[tid] * 3.f : 0.5f * (sTau[tid] + sThi[tid]); }
        else         { sThi[tid] = sTau[tid];
                       sTau[tid] = 0.5f * (sTlo[tid] + sTau[tid]); }
        sCnt[tid] = 0;
        sAny = 1;
      }
    }
    __syncthreads();
    if (!sAny) break;
  }

  if (tid < QPB) sSel[tid] = 0;
  __syncthreads();

  // ---- exact top-64 select (bisection on uint key) + weighted feature gather ----
  for (int qi = 0; qi < 2; ++qi) {
    const int lq = wv * 2 + qi;
    const int gq = qbase + lq;
    const int m  = min(sCnt[lq], CAP);

    if (m > KNN) {
      unsigned lo = 0u, hi = 0xffffffffu;
      for (int it = 0; it < 32; ++it) {
        unsigned mid = lo + ((hi - lo) >> 1);
        int c = 0;
        for (int j = lane; j < m; j += 64) c += (sCandK[lq][j] <= mid) ? 1 : 0;
        c = wave_sum(c);
        if (c >= KNN) hi = mid; else lo = mid + 1;
      }
      const unsigned K = lo;  // exact 64th-smallest key
      for (int j = lane; j < m; j += 64) {
        unsigned k = sCandK[lq][j];
        if (k < K) {
          int p = atomicAdd(&sSel[lq], 1);
          float dv = val_of(k);
          sFidx[lq][p] = sCandI[lq][j];
          sFw[lq][p]   = 1.f / (sqrtf(fmaxf(dv, 1e-12f)) + 1e-5f);
        }
      }
      for (int j = lane; j < m; j += 64) {   // ties at K fill remaining slots
        unsigned k = sCandK[lq][j];
        if (k == K) {
          int p = atomicAdd(&sSel[lq], 1);
          if (p < KNN) {
            float dv = val_of(k);
            sFidx[lq][p] = sCandI[lq][j];
            sFw[lq][p]   = 1.f / (sqrtf(fmaxf(dv, 1e-12f)) + 1e-5f);
          }
        }
      }
    } else {  // degenerate safety path
      for (int j = lane; j < m; j += 64) {
        unsigned k = sCandK[lq][j];
        int p = atomicAdd(&sSel[lq], 1);
        float dv = val_of(k);
        sFidx[lq][p] = sCandI[lq][j];
        sFw[lq][p]   = 1.f / (sqrtf(fmaxf(dv, 1e-12f)) + 1e-5f);
      }
    }
    int sc = min(sSel[lq], KNN);
    if (lane >= sc) { sFw[lq][lane] = 0.f; sFidx[lq][lane] = 0; }

    // each lane holds one (idx,w); broadcast via shfl, lane owns 2 channels
    const int   myI = sFidx[lq][lane];
    const float myW = sFw[lq][lane];
    float ax = 0.f, ay = 0.f;
    #pragma unroll 8
    for (int j = 0; j < KNN; ++j) {
      int   id = __shfl(myI, j, 64);
      float w  = __shfl(myW, j, 64);
      const float2 f2 = *(const float2*)(feat + ((size_t)id << 7) + (lane << 1));
      ax = fmaf(w, f2.x, ax);
      ay = fmaf(w, f2.y, ay);
    }
    *(float2*)(out + ((size_t)gq << 7) + (lane << 1)) = make_float2(ax, ay);
  }
}

extern "C" void kernel_launch(void* const* d_in, const int* in_sizes, int n_in,
                              void* d_out, int out_size, void* d_ws, size_t ws_size,
                              hipStream_t stream) {
  const float* qpos = (const float*)d_in[0];   // [8192,3]
  const float* feat = (const float*)d_in[1];   // [32768,128]
  const float* pos  = (const float*)d_in[2];   // [32768,3]
  float* out = (float*)d_out;                  // [8192,128]
  ft_knn_kernel<<<dim3(NBLK), dim3(256), 0, stream>>>(qpos, feat, pos, out);
}

// Round 3
// 143.482 us; speedup vs baseline: 1.9905x; 1.5165x over previous
//
#include <hip/hip_runtime.h>
#include <math.h>

#define NQ    8192
#define NPTS  32768
#define KNN   64
#define QPB   4             // queries per block; wave w owns query w in select phase
#define CAPW  56            // per-(wave,query) candidate segment capacity
#define NBLK  (NQ / QPB)    // 2048 blocks -> 8/CU resident (32 waves/CU)
#define PPW   (NPTS / 4)    // each of 4 waves scans 8192 points
#define NGRP  (PPW / 256)   // 32 groups of (64 lanes x 4 points)
#define MAXM  224           // max total candidates per query (4*CAPW)

// ---- order-preserving float<->uint key ----
__device__ __forceinline__ unsigned key_of(float f) {
  unsigned u = __float_as_uint(f);
  return (u & 0x80000000u) ? ~u : (u | 0x80000000u);
}
__device__ __forceinline__ float val_of(unsigned k) {
  unsigned u = (k & 0x80000000u) ? (k & 0x7fffffffu) : ~k;
  return __uint_as_float(u);
}
__device__ __forceinline__ int mbcnt64(unsigned long long m) {
  return __builtin_amdgcn_mbcnt_hi((unsigned)(m >> 32),
         __builtin_amdgcn_mbcnt_lo((unsigned)m, 0));
}
__device__ __forceinline__ float rflf(float x) {
  return __int_as_float(__builtin_amdgcn_readfirstlane(__float_as_int(x)));
}
__device__ __forceinline__ int rfli(int x) { return __builtin_amdgcn_readfirstlane(x); }

__device__ __forceinline__ float norm_cdf(float x) { return 0.5f * erfcf(-x * 0.70710678f); }
// Mass of standard 3D gaussian inside ball radius r centered at distance mu.
__device__ __forceinline__ float ball_mass(float mu, float r) {
  float a = r - mu, b = r + mu;
  float e = __expf(-0.5f * b * b) - __expf(-0.5f * a * a);
  return e / (mu * 2.50662827f) + norm_cdf(a) - norm_cdf(-mu) + norm_cdf(b) - norm_cdf(mu);
}

__global__ __launch_bounds__(256, 8) void ft_knn_kernel(
    const float* __restrict__ qpos, const float* __restrict__ feat,
    const float* __restrict__ pos, float* __restrict__ out) {

  __shared__ uint2 sCand[QPB][4][CAPW];   // (key, point idx) per query per wave-segment
  __shared__ uint2 sSel[QPB][KNN];        // (idx, weight bits)
  __shared__ int   sCntW[4][QPB];
  __shared__ float sQ[QPB][4];            // -2x, -2y, -2z, |q|^2
  __shared__ float sTau[QPB], sTlo[QPB], sThi[QPB];
  __shared__ int   sAct[QPB], sAny;

  const int tid   = threadIdx.x;
  const int lane  = tid & 63;
  const int wv    = tid >> 6;
  const int qbase = blockIdx.x * QPB;

  if (tid < QPB) {
    int gq = qbase + tid;
    float x = qpos[gq * 3 + 0], y = qpos[gq * 3 + 1], z = qpos[gq * 3 + 2];
    float b = x * x + y * y + z * z;
    sQ[tid][0] = -2.f * x; sQ[tid][1] = -2.f * y; sQ[tid][2] = -2.f * z; sQ[tid][3] = b;
    float mu = fmaxf(sqrtf(b), 0.05f);
    const float target = 110.0f / 32768.0f;   // E[cand]=110: P(<64) ~ 5e-6/query
    float lo = 0.f, hi = mu + 8.f;
    for (int i = 0; i < 16; ++i) {
      float r = 0.5f * (lo + hi);
      if (ball_mass(mu, r) < target) lo = r; else hi = r;
    }
    sTau[tid] = hi * hi;
    sTlo[tid] = 0.f; sThi[tid] = -1.f;
    sAct[tid] = 1;
  }
  __syncthreads();

  // ================= candidate scan (usually exactly 1 attempt) =================
  for (int attempt = 0; attempt < 12; ++attempt) {
    float qx[QPB], qy[QPB], qz[QPB], bq[QPB], tq[QPB]; int act[QPB], cnt[QPB];
    #pragma unroll
    for (int q = 0; q < QPB; ++q) {
      qx[q] = rflf(sQ[q][0]); qy[q] = rflf(sQ[q][1]); qz[q] = rflf(sQ[q][2]);
      bq[q] = rflf(sQ[q][3]);
      act[q] = rfli(sAct[q]);
      float tau = rflf(sTau[q]);
      tq[q] = act[q] ? (tau - bq[q]) : -1e30f;   // d' = d^2 - |q|^2 threshold
      cnt[q] = 0;
    }
    if (act[0] | act[1] | act[2] | act[3]) {
      const int pw = wv * PPW;
      for (int g = 0; g < NGRP; ++g) {
        const int pt = pw + g * 256 + lane * 4;
        const float* bp = pos + (size_t)pt * 3;
        const float4 A  = *(const float4*)(bp);
        const float4 B  = *(const float4*)(bp + 4);
        const float4 Cc = *(const float4*)(bp + 8);
        const float x0 = A.x,  y0 = A.y,  z0 = A.z;
        const float x1 = A.w,  y1 = B.x,  z1 = B.y;
        const float x2 = B.z,  y2 = B.w,  z2 = Cc.x;
        const float x3 = Cc.y, y3 = Cc.z, z3 = Cc.w;
        const float n0 = x0 * x0 + y0 * y0 + z0 * z0;
        const float n1 = x1 * x1 + y1 * y1 + z1 * z1;
        const float n2 = x2 * x2 + y2 * y2 + z2 * z2;
        const float n3 = x3 * x3 + y3 * y3 + z3 * z3;
        #pragma unroll
        for (int q = 0; q < QPB; ++q) {
          float d0 = fmaf(z0, qz[q], fmaf(y0, qy[q], fmaf(x0, qx[q], n0)));
          float d1 = fmaf(z1, qz[q], fmaf(y1, qy[q], fmaf(x1, qx[q], n1)));
          float d2 = fmaf(z2, qz[q], fmaf(y2, qy[q], fmaf(x2, qx[q], n2)));
          float d3 = fmaf(z3, qz[q], fmaf(y3, qy[q], fmaf(x3, qx[q], n3)));
          const bool h0 = d0 < tq[q], h1 = d1 < tq[q], h2 = d2 < tq[q], h3 = d3 < tq[q];
          const unsigned long long m0 = __ballot(h0), m1 = __ballot(h1),
                                   m2 = __ballot(h2), m3 = __ballot(h3);
          // per-slot scalar branches; no atomics, wave-private SGPR counter
          if (m0) { int p = cnt[q] + mbcnt64(m0);
                    if (h0 && p < CAPW) sCand[q][wv][p] = make_uint2(key_of(d0 + bq[q]), (unsigned)(pt + 0));
                    cnt[q] += (int)__popcll(m0); }
          if (m1) { int p = cnt[q] + mbcnt64(m1);
                    if (h1 && p < CAPW) sCand[q][wv][p] = make_uint2(key_of(d1 + bq[q]), (unsigned)(pt + 1));
                    cnt[q] += (int)__popcll(m1); }
          if (m2) { int p = cnt[q] + mbcnt64(m2);
                    if (h2 && p < CAPW) sCand[q][wv][p] = make_uint2(key_of(d2 + bq[q]), (unsigned)(pt + 2));
                    cnt[q] += (int)__popcll(m2); }
          if (m3) { int p = cnt[q] + mbcnt64(m3);
                    if (h3 && p < CAPW) sCand[q][wv][p] = make_uint2(key_of(d3 + bq[q]), (unsigned)(pt + 3));
                    cnt[q] += (int)__popcll(m3); }
        }
      }
    }
    __syncthreads();
    if (lane == 0) {
      #pragma unroll
      for (int q = 0; q < QPB; ++q) if (act[q]) sCntW[wv][q] = cnt[q];
    }
    if (tid == 0) sAny = 0;
    __syncthreads();
    if (tid < QPB && sAct[tid]) {
      int tot = 0, ovf = 0;
      #pragma unroll
      for (int w = 0; w < 4; ++w) { int c = sCntW[w][tid]; ovf |= (c > CAPW); tot += c; }
      if (!ovf && tot >= KNN && tot <= MAXM) sAct[tid] = 0;
      else {
        if (!ovf && tot < KNN) { sTlo[tid] = sTau[tid];
          sTau[tid] = (sThi[tid] < 0.f) ? sTau[tid] * 3.f : 0.5f * (sTau[tid] + sThi[tid]); }
        else { sThi[tid] = sTau[tid]; sTau[tid] = 0.5f * (sTlo[tid] + sTau[tid]); }
        sAny = 1;
      }
    }
    __syncthreads();
    if (!sAny) break;
  }

  // ================= exact top-64 select: wave wv handles query wv =================
  {
    const int q = wv;
    const int c0 = rfli(min(sCntW[0][q], CAPW));
    const int c1 = rfli(min(sCntW[1][q], CAPW));
    const int c2 = rfli(min(sCntW[2][q], CAPW));
    const int c3 = rfli(min(sCntW[3][q], CAPW));
    const int P1 = c0, P2 = P1 + c1, P3 = P2 + c2, m = P3 + c3;

    unsigned k[4], id[4];
    #pragma unroll
    for (int s = 0; s < 4; ++s) {      // compacted view -> registers, 4 slots/lane
      const int g = s * 64 + lane;
      const int ge1 = g >= P1, ge2 = g >= P2, ge3 = g >= P3;
      const int w = ge1 + ge2 + ge3;
      const int sb = ge3 ? P3 : (ge2 ? P2 : (ge1 ? P1 : 0));
      uint2 kv = make_uint2(0xFFFFFFFFu, 0u);
      if (g < m) kv = sCand[q][w][g - sb];
      k[s] = kv.x; id[s] = kv.y;
    }

    unsigned lo = 0u, hi = 0xFFFFFFFFu;    // bisect exact 64th-smallest key: ballots, no shfl
    for (int it = 0; it < 32; ++it) {
      unsigned mid = lo + ((hi - lo) >> 1);
      int c = (int)(__popcll(__ballot(k[0] <= mid)) + __popcll(__ballot(k[1] <= mid)) +
                    __popcll(__ballot(k[2] <= mid)) + __popcll(__ballot(k[3] <= mid)));
      if (c >= KNN) hi = mid; else lo = mid + 1;
    }
    const unsigned K = lo;

    int fill = 0;
    #pragma unroll
    for (int s = 0; s < 4; ++s) {
      const bool lt = k[s] < K;
      const unsigned long long msk = __ballot(lt);
      if (msk) {
        const int p = fill + mbcnt64(msk);
        if (lt) { float dv = val_of(k[s]);
                  float w_ = 1.f / (sqrtf(fmaxf(dv, 1e-12f)) + 1e-5f);
                  sSel[q][p] = make_uint2(id[s], __float_as_uint(w_)); }
        fill += (int)__popcll(msk);
      }
    }
    #pragma unroll
    for (int s = 0; s < 4; ++s) {          // ties at K fill remaining slots
      const bool eq = (k[s] == K);
      const unsigned long long msk = __ballot(eq);
      if (msk) {
        const int p = fill + mbcnt64(msk);
        if (eq && p < KNN) { float dv = val_of(k[s]);
                             float w_ = 1.f / (sqrtf(fmaxf(dv, 1e-12f)) + 1e-5f);
                             sSel[q][p] = make_uint2(id[s], __float_as_uint(w_)); }
        fill += (int)__popcll(msk);
      }
    }
  }

  // ================= weighted feature gather (same wave, no barrier) =================
  {
    const int q = wv, gq = qbase + wv;
    float ax = 0.f, ay = 0.f;
    #pragma unroll 8
    for (int j = 0; j < KNN; ++j) {
      const uint2 pr = sSel[q][j];          // broadcast LDS read
      const float w = __uint_as_float(pr.y);
      const float2 f2 = *(const float2*)(feat + ((size_t)pr.x << 7) + (lane << 1));
      ax = fmaf(w, f2.x, ax);
      ay = fmaf(w, f2.y, ay);
    }
    *(float2*)(out + ((size_t)gq << 7) + (lane << 1)) = make_float2(ax, ay);
  }
}

extern "C" void kernel_launch(void* const* d_in, const int* in_sizes, int n_in,
                              void* d_out, int out_size, void* d_ws, size_t ws_size,
                              hipStream_t stream) {
  const float* qpos = (const float*)d_in[0];   // [8192,3]
  const float* feat = (const float*)d_in[1];   // [32768,128]
  const float* pos  = (const float*)d_in[2];   // [32768,3]
  float* out = (float*)d_out;                  // [8192,128]
  ft_knn_kernel<<<dim3(NBLK), dim3(256), 0, stream>>>(qpos, feat, pos, out);
}